// Round 1
// baseline (24.030 us; speedup 1.0000x reference)
//
#include <hip/hip_runtime.h>

#define N_NODES 1024
#define B_SZ 16
#define F_SZ 50

// Kernel 1: compute 6-bit port_has_track mask per (b, n).
// bits[b*N + n] bit p = (sum_f nf[b,n,f] * mask[f,p]) > 0
__global__ void ports_kernel(const float* __restrict__ nf,
                             const float* __restrict__ mask,
                             unsigned char* __restrict__ bits) {
    __shared__ float smask[F_SZ * 6];
    for (int t = threadIdx.x; t < F_SZ * 6; t += blockDim.x)
        smask[t] = mask[t];
    __syncthreads();

    int idx = blockIdx.x * blockDim.x + threadIdx.x;  // b*N + n
    if (idx >= B_SZ * N_NODES) return;
    const float* row = nf + (size_t)idx * F_SZ;

    float acc[6] = {0.f, 0.f, 0.f, 0.f, 0.f, 0.f};
    for (int f = 0; f < F_SZ; ++f) {
        float v = row[f];
        #pragma unroll
        for (int p = 0; p < 6; ++p)
            acc[p] += v * smask[f * 6 + p];
    }
    unsigned char b = 0;
    #pragma unroll
    for (int p = 0; p < 6; ++p)
        if (acc[p] > 0.0f) b |= (unsigned char)(1u << p);
    bits[idx] = b;
}

// Kernel 2: out[b,i,j] = src_bit(b,i,dir') & dst_bit(b,j,opp') & (dir != 6)
// block = row i (1024 blocks), thread = 4 consecutive columns (256 threads).
__global__ void connect_kernel(const int* __restrict__ dir,
                               const unsigned char* __restrict__ bits,
                               float* __restrict__ out) {
    const int i = blockIdx.x;
    const int j4 = threadIdx.x;  // each handles columns [j4*4, j4*4+3]

    int4 d = ((const int4*)(dir + (size_t)i * N_NODES))[j4];
    int dv[4] = {d.x, d.y, d.z, d.w};
    unsigned ds[4], os[4], am[4];
    #pragma unroll
    for (int k = 0; k < 4; ++k) {
        am[k] = (dv[k] != 6) ? 1u : 0u;
        ds[k] = (unsigned)min(dv[k], 5);
        os[k] = (unsigned)min((dv[k] + 3) % 6, 5);
    }

    #pragma unroll
    for (int b = 0; b < B_SZ; ++b) {
        unsigned s = bits[b * N_NODES + i];                       // wave-uniform
        uchar4 t = ((const uchar4*)(bits + b * N_NODES))[j4];     // coalesced
        unsigned tb[4] = {t.x, t.y, t.z, t.w};
        float4 o;
        float* op = (float*)&o;
        #pragma unroll
        for (int k = 0; k < 4; ++k)
            op[k] = ((s >> ds[k]) & (tb[k] >> os[k]) & am[k] & 1u) ? 1.0f : 0.0f;
        ((float4*)(out + (size_t)b * N_NODES * N_NODES + (size_t)i * N_NODES))[j4] = o;
    }
}

extern "C" void kernel_launch(void* const* d_in, const int* in_sizes, int n_in,
                              void* d_out, int out_size, void* d_ws, size_t ws_size,
                              hipStream_t stream) {
    const float* nf   = (const float*)d_in[0];   // (16, 1024, 50) f32
    const int*   dir  = (const int*)d_in[1];     // (1024, 1024) i32
    const float* mask = (const float*)d_in[2];   // (50, 6) f32
    float* out = (float*)d_out;                  // (16, 1024, 1024) f32
    unsigned char* bits = (unsigned char*)d_ws;  // 16 KB scratch

    ports_kernel<<<(B_SZ * N_NODES + 255) / 256, 256, 0, stream>>>(nf, mask, bits);
    connect_kernel<<<N_NODES, 256, 0, stream>>>(dir, bits, out);
}